// Round 10
// baseline (255.267 us; speedup 1.0000x reference)
//
#include <hip/hip_runtime.h>
#include <hip/hip_bf16.h>
#include <math.h>

#define D_MODEL 512
#define N_HEADS 8
#define D_K     64
#define T_SEQ   2048
#define B_SZ    4
#define M_ROWS  (B_SZ * T_SEQ)   // 8192

typedef __bf16 bf16;
typedef __bf16 bf16x4 __attribute__((ext_vector_type(4)));
typedef __bf16 bf16x8 __attribute__((ext_vector_type(8)));
typedef float  floatx4 __attribute__((ext_vector_type(4)));

// 16B-atom XOR swizzle for stride-64 bf16 LDS tiles: conflict-free b128
// fragment access (padding cannot fix b128 tiles: stride%4dw==0 -> 8-way).
__device__ __forceinline__ int SWZ(int row, int col) {
  return row * 64 + ((((col >> 3) ^ (row & 7)) << 3) | (col & 7));
}

// ---------------------------------------------------------------------------
// prep: fused LayerNorm (blocks 0..8191) + weight f32->bf16 convert
// (blocks 8192..9215). Saves one dispatch (~8us fixed overhead).
// ---------------------------------------------------------------------------
__global__ __launch_bounds__(256) void prep(
    const float* __restrict__ x, const float* __restrict__ g,
    const float* __restrict__ b, bf16* __restrict__ out,
    const float* __restrict__ wq, const float* __restrict__ wk,
    const float* __restrict__ wv, const float* __restrict__ wo,
    bf16* __restrict__ wdst) {
  int bid = blockIdx.x;
  int tid = threadIdx.x;
  if (bid >= M_ROWS) {
    int gid = (bid - M_ROWS) * 256 + tid;
    int e0  = gid * 4;
    int mat = e0 >> 18;
    int loc = e0 & 262143;
    const float* src = (mat == 0) ? wq : (mat == 1) ? wk : (mat == 2) ? wv : wo;
    float4 v = *(const float4*)(src + loc);
    bf16* d = wdst + e0;
    d[0] = (bf16)v.x; d[1] = (bf16)v.y; d[2] = (bf16)v.z; d[3] = (bf16)v.w;
    return;
  }
  const float* xr = x + (size_t)bid * D_MODEL;
  float2 v = *(const float2*)(xr + 2 * tid);
  float s = v.x + v.y, ss = v.x * v.x + v.y * v.y;
  for (int off = 32; off; off >>= 1) {
    s  += __shfl_down(s,  off, 64);
    ss += __shfl_down(ss, off, 64);
  }
  __shared__ float ps[4], pss[4], stats[2];
  int wave = tid >> 6, lane = tid & 63;
  if (lane == 0) { ps[wave] = s; pss[wave] = ss; }
  __syncthreads();
  if (tid == 0) {
    float S  = ps[0] + ps[1] + ps[2] + ps[3];
    float SS = pss[0] + pss[1] + pss[2] + pss[3];
    float mu  = S / (float)D_MODEL;
    float var = SS / (float)D_MODEL - mu * mu;
    stats[0] = mu;
    stats[1] = rsqrtf(var + 1e-5f);
  }
  __syncthreads();
  float mu = stats[0], rs = stats[1];
  float2 gg = *(const float2*)(g + 2 * tid);
  float2 bb = *(const float2*)(b + 2 * tid);
  bf16* orow = out + (size_t)bid * D_MODEL;
  orow[2 * tid]     = (bf16)((v.x - mu) * rs * gg.x + bb.x);
  orow[2 * tid + 1] = (bf16)((v.y - mu) * rs * gg.y + bb.y);
}

// ---------------------------------------------------------------------------
// Sinusoidal PE value for (t, d), d in [0,64).
// ---------------------------------------------------------------------------
__device__ __forceinline__ float pe_val(int t, int d) {
  int i2 = d & ~1;
  float div = expf((float)i2 * (-0.1439115683f));  // -ln(10000)/64
  float ang = (float)t * div;
  return (d & 1) ? cosf(ang) : sinf(ang);
}

// ---------------------------------------------------------------------------
// QKV projection GEMM — direct-from-global K-loop with explicit 1-step
// register double-buffering (R8 PMC: VGPR=48 -> compiler serialized the 6
// loads/k-step behind MFMA; prefetch forces them in flight, ~+48 VGPRs).
// Grid (64, 24): block = 128m x 64n of ONE matrix, wave 32m x 64n.
// Epilogue via wave-private LDS transpose -> full-line b128 stores.
// ---------------------------------------------------------------------------
__global__ __launch_bounds__(256, 4) void gemm_qkv(
    const bf16* __restrict__ A, const bf16* __restrict__ wqkv,
    const float* __restrict__ bq, const float* __restrict__ bk, const float* __restrict__ bv,
    bf16* __restrict__ Qo, bf16* __restrict__ Ko, bf16* __restrict__ VTo) {
  __shared__ bf16 ep[4][2560];           // 20 KB epilogue scratch
  int wave = threadIdx.x >> 6, lane = threadIdx.x & 63;
  int lm = lane & 15, quad = lane >> 4;
  int n0g  = blockIdx.y * 64;            // 0..1535
  int mat  = n0g >> 9;                   // 0=Q,1=K,2=V
  int nloc = n0g & 511;                  // h*64
  int h    = nloc >> 6;
  const bf16* W = wqkv + (size_t)mat * D_MODEL * D_MODEL;
  int m0 = blockIdx.x * 128 + wave * 32;
  const bf16* ap0 = A + (size_t)(m0 + lm) * D_MODEL + quad * 8;
  const bf16* ap1 = ap0 + (size_t)16 * D_MODEL;
  const bf16* bp0 = W + (size_t)(nloc + lm) * D_MODEL + quad * 8;

  floatx4 acc[2][4];
#pragma unroll
  for (int mi = 0; mi < 2; mi++)
#pragma unroll
    for (int nt = 0; nt < 4; nt++) acc[mi][nt] = floatx4{0.f, 0.f, 0.f, 0.f};

  bf16x8 a0c = *(const bf16x8*)(ap0);
  bf16x8 a1c = *(const bf16x8*)(ap1);
  bf16x8 bc[4];
#pragma unroll
  for (int nt = 0; nt < 4; nt++)
    bc[nt] = *(const bf16x8*)(bp0 + nt * 8192);

#pragma unroll
  for (int k = 0; k < D_MODEL; k += 32) {
    bf16x8 a0n, a1n, bn[4];
    if (k + 32 < D_MODEL) {
      a0n = *(const bf16x8*)(ap0 + k + 32);
      a1n = *(const bf16x8*)(ap1 + k + 32);
#pragma unroll
      for (int nt = 0; nt < 4; nt++)
        bn[nt] = *(const bf16x8*)(bp0 + nt * 8192 + k + 32);
    }
#pragma unroll
    for (int nt = 0; nt < 4; nt++) {
      acc[0][nt] = __builtin_amdgcn_mfma_f32_16x16x32_bf16(a0c, bc[nt], acc[0][nt], 0, 0, 0);
      acc[1][nt] = __builtin_amdgcn_mfma_f32_16x16x32_bf16(a1c, bc[nt], acc[1][nt], 0, 0, 0);
    }
    if (k + 32 < D_MODEL) {
      a0c = a0n; a1c = a1n;
#pragma unroll
      for (int nt = 0; nt < 4; nt++) bc[nt] = bn[nt];
    }
  }

  int bb = m0 >> 11, t0 = m0 & (T_SEQ - 1);   // this wave's 32-t slice start
  size_t bhoff = (size_t)(bb * N_HEADS + h) * (T_SEQ * D_K);
  bf16* myep = ep[wave];

  if (mat == 2) {
    // ---- V -> VT[bh][d][t]: tile [64 d][32 t], stride 40 ----
#pragma unroll
    for (int nt = 0; nt < 4; nt++) {
      int d = nt * 16 + lm;
      float bvv = bv[nloc + d];
#pragma unroll
      for (int mi = 0; mi < 2; mi++) {
        bf16x4 pk;
#pragma unroll
        for (int rr = 0; rr < 4; rr++) pk[rr] = (bf16)(acc[mi][nt][rr] + bvv);
        *(bf16x4*)&myep[d * 40 + mi * 16 + quad * 4] = pk;
      }
    }
#pragma unroll
    for (int rd = 0; rd < 4; rd++) {
      int d = rd * 16 + (lane >> 2);
      bf16x8 v = *(const bf16x8*)&myep[d * 40 + (lane & 3) * 8];
      *(bf16x8*)(VTo + bhoff + (size_t)d * T_SEQ + t0 + (lane & 3) * 8) = v;
    }
  } else {
    // ---- Q or K -> [bh][t][d]: tile [32 t][64 d], stride 72 ----
    bf16* dst = (mat == 0) ? Qo : Ko;
    const float* bias = (mat == 0) ? bq : bk;
#pragma unroll
    for (int nt = 0; nt < 4; nt++) {
      int d = nt * 16 + lm;
      float bval = bias[nloc + d];
#pragma unroll
      for (int mi = 0; mi < 2; mi++) {
#pragma unroll
        for (int rr = 0; rr < 4; rr++) {
          int tl = mi * 16 + quad * 4 + rr;
          float v = acc[mi][nt][rr] + bval;
          if (mat == 1) v += pe_val(t0 + tl, d);
          else          v *= 0.125f;   // fold 1/sqrt(dk) into Q
          myep[tl * 72 + d] = (bf16)v;
        }
      }
    }
#pragma unroll
    for (int rd = 0; rd < 4; rd++) {
      int row = rd * 8 + (lane >> 3);
      bf16x8 v = *(const bf16x8*)&myep[row * 72 + (lane & 7) * 8];
      *(bf16x8*)(dst + bhoff + (size_t)(t0 + row) * D_K + (lane & 7) * 8) = v;
    }
  }
}

// ---------------------------------------------------------------------------
// Output projection GEMM — direct-from-global + register prefetch,
// retiled 32m x 32n per wave (4096 waves = 16/CU; R8 had only 8/CU).
// Grid (64, 16): block = 128m x 32n. f32 stores are full-line.
// ---------------------------------------------------------------------------
__global__ __launch_bounds__(256, 4) void gemm_out(const bf16* __restrict__ A,
                                                   const bf16* __restrict__ W,
                                                   const float* __restrict__ bias,
                                                   float* __restrict__ out) {
  int wave = threadIdx.x >> 6, lane = threadIdx.x & 63;
  int lm = lane & 15, quad = lane >> 4;
  int n0 = blockIdx.y * 32;
  int m0 = blockIdx.x * 128 + wave * 32;
  const bf16* ap0 = A + (size_t)(m0 + lm) * D_MODEL + quad * 8;
  const bf16* ap1 = ap0 + (size_t)16 * D_MODEL;
  const bf16* bp0 = W + (size_t)(n0 + lm) * D_MODEL + quad * 8;

  floatx4 acc[2][2];
#pragma unroll
  for (int mi = 0; mi < 2; mi++)
#pragma unroll
    for (int nt = 0; nt < 2; nt++) acc[mi][nt] = floatx4{0.f, 0.f, 0.f, 0.f};

  bf16x8 a0c = *(const bf16x8*)(ap0);
  bf16x8 a1c = *(const bf16x8*)(ap1);
  bf16x8 bc[2];
#pragma unroll
  for (int nt = 0; nt < 2; nt++)
    bc[nt] = *(const bf16x8*)(bp0 + nt * 8192);

#pragma unroll
  for (int k = 0; k < D_MODEL; k += 32) {
    bf16x8 a0n, a1n, bn[2];
    if (k + 32 < D_MODEL) {
      a0n = *(const bf16x8*)(ap0 + k + 32);
      a1n = *(const bf16x8*)(ap1 + k + 32);
#pragma unroll
      for (int nt = 0; nt < 2; nt++)
        bn[nt] = *(const bf16x8*)(bp0 + nt * 8192 + k + 32);
    }
#pragma unroll
    for (int nt = 0; nt < 2; nt++) {
      acc[0][nt] = __builtin_amdgcn_mfma_f32_16x16x32_bf16(a0c, bc[nt], acc[0][nt], 0, 0, 0);
      acc[1][nt] = __builtin_amdgcn_mfma_f32_16x16x32_bf16(a1c, bc[nt], acc[1][nt], 0, 0, 0);
    }
    if (k + 32 < D_MODEL) {
      a0c = a0n; a1c = a1n;
#pragma unroll
      for (int nt = 0; nt < 2; nt++) bc[nt] = bn[nt];
    }
  }
#pragma unroll
  for (int nt = 0; nt < 2; nt++) {
    int n = n0 + nt * 16 + lm;
    float bval = bias[n];
#pragma unroll
    for (int mi = 0; mi < 2; mi++)
#pragma unroll
      for (int rr = 0; rr < 4; rr++) {
        int m = m0 + mi * 16 + quad * 4 + rr;
        out[(size_t)m * D_MODEL + n] = acc[mi][nt][rr] + bval;
      }
  }
}

// ---------------------------------------------------------------------------
// MFMA flash attention v3 (unchanged from R8; register-prefetch staging
// validated by R5->R7 delta).
// ---------------------------------------------------------------------------
__global__ __launch_bounds__(256) void flash_mfma(const bf16* __restrict__ Q,
                                                  const bf16* __restrict__ K,
                                                  const bf16* __restrict__ VT,
                                                  bf16* __restrict__ ctx) {
  __shared__ bf16 sK[64 * 64];          // [key][d]   8 KB, swizzled
  __shared__ bf16 sVT[64 * 64];         // [d][key]   8 KB, swizzled
  __shared__ bf16 sP[4][32 * 64];       // per-wave [q][key] 16 KB, swizzled

  int tid  = threadIdx.x;
  int wave = tid >> 6, lane = tid & 63;
  int lm = lane & 15, quad = lane >> 4;
  int bh = blockIdx.y;
  int q0 = blockIdx.x * 128 + wave * 32;

  const bf16* Qb  = Q  + (size_t)bh * T_SEQ * D_K;
  const bf16* Kb  = K  + (size_t)bh * T_SEQ * D_K;
  const bf16* VTb = VT + (size_t)bh * T_SEQ * D_K;  // [d][t]

  bf16x8 qf[2][2];
#pragma unroll
  for (int qt = 0; qt < 2; qt++)
#pragma unroll
    for (int kb = 0; kb < 2; kb++)
      qf[qt][kb] = *(const bf16x8*)(Qb + (size_t)(q0 + qt * 16 + lm) * D_K + kb * 32 + quad * 8);

  floatx4 o[2][4];
#pragma unroll
  for (int qt = 0; qt < 2; qt++)
#pragma unroll
    for (int nt = 0; nt < 4; nt++) o[qt][nt] = floatx4{0.f, 0.f, 0.f, 0.f};
  float l_i[2] = {0.f, 0.f};

  int srow = wave * 16 + (lane >> 2);
  int scol = (lane & 3) * 16;
  const bf16* kp0 = Kb  + (size_t)srow * D_K + scol;
  const bf16* vp0 = VTb + (size_t)srow * T_SEQ + scol;

  bf16x8 rk0 = *(const bf16x8*)(kp0);
  bf16x8 rk1 = *(const bf16x8*)(kp0 + 8);
  bf16x8 rv0 = *(const bf16x8*)(vp0);
  bf16x8 rv1 = *(const bf16x8*)(vp0 + 8);

  for (int kt = 0; kt < T_SEQ / 64; kt++) {
    __syncthreads();
    *(bf16x8*)&sK[SWZ(srow, scol)]      = rk0;
    *(bf16x8*)&sK[SWZ(srow, scol + 8)]  = rk1;
    *(bf16x8*)&sVT[SWZ(srow, scol)]     = rv0;
    *(bf16x8*)&sVT[SWZ(srow, scol + 8)] = rv1;
    if (kt + 1 < T_SEQ / 64) {
      const bf16* kp = kp0 + (size_t)(kt + 1) * 64 * D_K;
      const bf16* vp = vp0 + (size_t)(kt + 1) * 64;
      rk0 = *(const bf16x8*)(kp);
      rk1 = *(const bf16x8*)(kp + 8);
      rv0 = *(const bf16x8*)(vp);
      rv1 = *(const bf16x8*)(vp + 8);
    }
    __syncthreads();

    floatx4 s[2][4];
#pragma unroll
    for (int qt = 0; qt < 2; qt++)
#pragma unroll
      for (int nt = 0; nt < 4; nt++) s[qt][nt] = floatx4{0.f, 0.f, 0.f, 0.f};
#pragma unroll
    for (int kb = 0; kb < 2; kb++) {
#pragma unroll
      for (int nt = 0; nt < 4; nt++) {
        bf16x8 kf = *(const bf16x8*)&sK[SWZ(nt * 16 + lm, kb * 32 + quad * 8)];
        s[0][nt] = __builtin_amdgcn_mfma_f32_16x16x32_bf16(kf, qf[0][kb], s[0][nt], 0, 0, 0);
        s[1][nt] = __builtin_amdgcn_mfma_f32_16x16x32_bf16(kf, qf[1][kb], s[1][nt], 0, 0, 0);
      }
    }

#pragma unroll
    for (int qt = 0; qt < 2; qt++) {
      float ls = 0.f;
      bf16x4 pk[4];
#pragma unroll
      for (int nt = 0; nt < 4; nt++) {
#pragma unroll
        for (int rr = 0; rr < 4; rr++) {
          float p = __expf(s[qt][nt][rr] - 8.0f);
          ls += p;
          pk[nt][rr] = (bf16)p;
        }
      }
#pragma unroll
      for (int nt = 0; nt < 4; nt++)
        *(bf16x4*)&sP[wave][SWZ(qt * 16 + lm, nt * 16 + quad * 4)] = pk[nt];
      ls += __shfl_xor(ls, 16, 64);
      ls += __shfl_xor(ls, 32, 64);
      l_i[qt] += ls;
    }

#pragma unroll
    for (int kb = 0; kb < 2; kb++) {
      bf16x8 pf0 = *(const bf16x8*)&sP[wave][SWZ(lm, kb * 32 + quad * 8)];
      bf16x8 pf1 = *(const bf16x8*)&sP[wave][SWZ(16 + lm, kb * 32 + quad * 8)];
#pragma unroll
      for (int nt = 0; nt < 4; nt++) {
        bf16x8 vt = *(const bf16x8*)&sVT[SWZ(nt * 16 + lm, kb * 32 + quad * 8)];
        o[0][nt] = __builtin_amdgcn_mfma_f32_16x16x32_bf16(pf0, vt, o[0][nt], 0, 0, 0);
        o[1][nt] = __builtin_amdgcn_mfma_f32_16x16x32_bf16(pf1, vt, o[1][nt], 0, 0, 0);
      }
    }
  }

  int b_ = bh >> 3, h = bh & 7;
#pragma unroll
  for (int qt = 0; qt < 2; qt++) {
#pragma unroll
    for (int rr = 0; rr < 4; rr++) {
      int qq = quad * 4 + rr;
      float linv = 1.f / __shfl(l_i[qt], qq, 64);
      int t = q0 + qt * 16 + qq;
      bf16* op = ctx + ((size_t)(b_ * T_SEQ + t)) * D_MODEL + h * D_K;
#pragma unroll
      for (int nt = 0; nt < 4; nt++)
        op[nt * 16 + lm] = (bf16)(o[qt][nt][rr] * linv);
    }
  }
}

// ---------------------------------------------------------------------------
extern "C" void kernel_launch(void* const* d_in, const int* in_sizes, int n_in,
                              void* d_out, int out_size, void* d_ws, size_t ws_size,
                              hipStream_t stream) {
  const float* x    = (const float*)d_in[0];
  const float* ln_g = (const float*)d_in[1];
  const float* ln_b = (const float*)d_in[2];
  const float* wq   = (const float*)d_in[3];
  const float* bq   = (const float*)d_in[4];
  const float* wk   = (const float*)d_in[5];
  const float* bk   = (const float*)d_in[6];
  const float* wv   = (const float*)d_in[7];
  const float* bv   = (const float*)d_in[8];
  const float* wo   = (const float*)d_in[9];
  const float* bo   = (const float*)d_in[10];
  float* out = (float*)d_out;

  char* ws = (char*)d_ws;
  const size_t MB8 = (size_t)M_ROWS * D_MODEL * sizeof(bf16);  // 8 MB
  bf16* normed = (bf16*)(ws);                    // dead after gemm_qkv
  bf16* Qb     = (bf16*)(ws + MB8);
  bf16* Kb     = (bf16*)(ws + 2 * MB8);
  bf16* VTb    = (bf16*)(ws + 3 * MB8);          // V^T: [bh][d][t]
  bf16* w4     = (bf16*)(ws + 4 * MB8);          // 2 MB: wq|wk|wv|wo bf16
  bf16* ctx    = normed;                         // alias; ws total 34 MB

  prep<<<M_ROWS + 1024, 256, 0, stream>>>(x, ln_g, ln_b, normed,
                                          wq, wk, wv, wo, w4);
  gemm_qkv<<<dim3(M_ROWS / 128, 24), 256, 0, stream>>>(
      normed, w4, bq, bk, bv, Qb, Kb, VTb);
  flash_mfma<<<dim3(T_SEQ / 128, B_SZ * N_HEADS), 256, 0, stream>>>(Qb, Kb, VTb, ctx);
  gemm_out<<<dim3(M_ROWS / 128, D_MODEL / 32), 256, 0, stream>>>(
      ctx, w4 + 3 * (size_t)D_MODEL * D_MODEL, bo, out);
}

// Round 11
// 211.781 us; speedup vs baseline: 1.2053x; 1.2053x over previous
//
#include <hip/hip_runtime.h>
#include <hip/hip_bf16.h>
#include <math.h>

#define D_MODEL 512
#define N_HEADS 8
#define D_K     64
#define T_SEQ   2048
#define B_SZ    4
#define M_ROWS  (B_SZ * T_SEQ)   // 8192

typedef __bf16 bf16;
typedef __bf16 bf16x4 __attribute__((ext_vector_type(4)));
typedef __bf16 bf16x8 __attribute__((ext_vector_type(8)));
typedef float  floatx4 __attribute__((ext_vector_type(4)));

// 16B-atom XOR swizzle for stride-64 bf16 LDS tiles: conflict-free b128
// fragment access (padding cannot fix b128 tiles: stride%4dw==0 -> 8-way).
__device__ __forceinline__ int SWZ(int row, int col) {
  return row * 64 + ((((col >> 3) ^ (row & 7)) << 3) | (col & 7));
}

// ---------------------------------------------------------------------------
// prep: fused LayerNorm (blocks 0..8191) + weight f32->bf16 convert.
// ---------------------------------------------------------------------------
__global__ __launch_bounds__(256) void prep(
    const float* __restrict__ x, const float* __restrict__ g,
    const float* __restrict__ b, bf16* __restrict__ out,
    const float* __restrict__ wq, const float* __restrict__ wk,
    const float* __restrict__ wv, const float* __restrict__ wo,
    bf16* __restrict__ wdst) {
  int bid = blockIdx.x;
  int tid = threadIdx.x;
  if (bid >= M_ROWS) {
    int gid = (bid - M_ROWS) * 256 + tid;
    int e0  = gid * 4;
    int mat = e0 >> 18;
    int loc = e0 & 262143;
    const float* src = (mat == 0) ? wq : (mat == 1) ? wk : (mat == 2) ? wv : wo;
    float4 v = *(const float4*)(src + loc);
    bf16* d = wdst + e0;
    d[0] = (bf16)v.x; d[1] = (bf16)v.y; d[2] = (bf16)v.z; d[3] = (bf16)v.w;
    return;
  }
  const float* xr = x + (size_t)bid * D_MODEL;
  float2 v = *(const float2*)(xr + 2 * tid);
  float s = v.x + v.y, ss = v.x * v.x + v.y * v.y;
  for (int off = 32; off; off >>= 1) {
    s  += __shfl_down(s,  off, 64);
    ss += __shfl_down(ss, off, 64);
  }
  __shared__ float ps[4], pss[4], stats[2];
  int wave = tid >> 6, lane = tid & 63;
  if (lane == 0) { ps[wave] = s; pss[wave] = ss; }
  __syncthreads();
  if (tid == 0) {
    float S  = ps[0] + ps[1] + ps[2] + ps[3];
    float SS = pss[0] + pss[1] + pss[2] + pss[3];
    float mu  = S / (float)D_MODEL;
    float var = SS / (float)D_MODEL - mu * mu;
    stats[0] = mu;
    stats[1] = rsqrtf(var + 1e-5f);
  }
  __syncthreads();
  float mu = stats[0], rs = stats[1];
  float2 gg = *(const float2*)(g + 2 * tid);
  float2 bb = *(const float2*)(b + 2 * tid);
  bf16* orow = out + (size_t)bid * D_MODEL;
  orow[2 * tid]     = (bf16)((v.x - mu) * rs * gg.x + bb.x);
  orow[2 * tid + 1] = (bf16)((v.y - mu) * rs * gg.y + bb.y);
}

// ---------------------------------------------------------------------------
// Sinusoidal PE value for (t, d), d in [0,64).
// ---------------------------------------------------------------------------
__device__ __forceinline__ float pe_val(int t, int d) {
  int i2 = d & ~1;
  float div = expf((float)i2 * (-0.1439115683f));  // -ln(10000)/64
  float ang = (float)t * div;
  return (d & 1) ? cosf(ang) : sinf(ang);
}

// ---------------------------------------------------------------------------
// QKV projection v4 — WEIGHTS-RESIDENT LDS GEMM.
// R10 forensics: direct-global K-loop serialized ~1000cyc/load in-wave
// (VGPR=48, compiler recycles regs; 96 loads/wave ~= 81us). Fix: stage the
// whole W n-slice (64x512 = 64KB) in LDS ONCE (single barrier), then the
// m-loop does only 2 batched A-loads + 4 ds_read per 8 MFMAs; A-loads are
// 32 independent regs (af[2][16]) -> no recycling chain.
// Grid (32, 24): by>>3 = mat, by&7 = head. Block = 4 waves, 2 m-iters of
// 128m (wave 32m x 64n). LDS 64KB W + 12KB chunked epilogue = 76KB, 2/CU.
// ---------------------------------------------------------------------------
__global__ __launch_bounds__(256, 2) void gemm_qkv(
    const bf16* __restrict__ A, const bf16* __restrict__ wqkv,
    const float* __restrict__ bq, const float* __restrict__ bk, const float* __restrict__ bv,
    bf16* __restrict__ Qo, bf16* __restrict__ Ko, bf16* __restrict__ VTo) {
  __shared__ bf16 sW[32768];             // 8 tiles of [64n][64k], swizzled
  __shared__ bf16 ep[4][1536];           // per-wave epilogue chunks (12 KB)

  int tid = threadIdx.x;
  int w = tid >> 6, lane = tid & 63;
  int lm = lane & 15, quad = lane >> 4;
  int mat  = blockIdx.y >> 3;            // 0=Q,1=K,2=V
  int h    = blockIdx.y & 7;
  int nloc = h * 64;
  const bf16* Wp = wqkv + (size_t)mat * 262144;

  // ---- stage W slice once: rows nloc..nloc+63, all k ----
  {
    int row = tid >> 2;
    int cc  = (tid & 3) * 16;
#pragma unroll
    for (int kc = 0; kc < 8; kc++) {
      const bf16* src = Wp + (size_t)(nloc + row) * D_MODEL + kc * 64 + cc;
      bf16x8 w0 = *(const bf16x8*)src;
      bf16x8 w1 = *(const bf16x8*)(src + 8);
      *(bf16x8*)&sW[kc * 4096 + SWZ(row, cc)]     = w0;
      *(bf16x8*)&sW[kc * 4096 + SWZ(row, cc + 8)] = w1;
    }
  }
  __syncthreads();   // only barrier in the kernel

  for (int it = 0; it < 2; it++) {
    int mbase = blockIdx.x * 256 + it * 128 + w * 32;
    const bf16* ap = A + (size_t)(mbase + lm) * D_MODEL + quad * 8;

    // ---- batched A-loads: 32 independent b128s, all in flight ----
    bf16x8 af[2][16];
#pragma unroll
    for (int mi = 0; mi < 2; mi++)
#pragma unroll
      for (int ks = 0; ks < 16; ks++)
        af[mi][ks] = *(const bf16x8*)(ap + mi * 16 * D_MODEL + ks * 32);

    floatx4 acc[2][4];
#pragma unroll
    for (int mi = 0; mi < 2; mi++)
#pragma unroll
      for (int nt = 0; nt < 4; nt++) acc[mi][nt] = floatx4{0.f, 0.f, 0.f, 0.f};

#pragma unroll
    for (int ks = 0; ks < 16; ks++) {
#pragma unroll
      for (int nt = 0; nt < 4; nt++) {
        bf16x8 bfr = *(const bf16x8*)
            &sW[(ks >> 1) * 4096 + SWZ(nt * 16 + lm, (ks & 1) * 32 + quad * 8)];
        acc[0][nt] = __builtin_amdgcn_mfma_f32_16x16x32_bf16(af[0][ks], bfr, acc[0][nt], 0, 0, 0);
        acc[1][nt] = __builtin_amdgcn_mfma_f32_16x16x32_bf16(af[1][ks], bfr, acc[1][nt], 0, 0, 0);
      }
    }

    // ---- epilogue (wave-private ep chunks; no barrier: sW untouched) ----
    int bb = mbase >> 11, t0w = mbase & (T_SEQ - 1);
    size_t bhoff = (size_t)(bb * N_HEADS + h) * (T_SEQ * D_K);
    bf16* myep = ep[w];

    if (mat == 2) {
      // V -> VT[bh][d][t]: 4 chunks of [16 d][32 t], stride 40
#pragma unroll
      for (int nt = 0; nt < 4; nt++) {
        float bvv = bv[nloc + nt * 16 + lm];
#pragma unroll
        for (int mi = 0; mi < 2; mi++) {
          bf16x4 pk;
#pragma unroll
          for (int rr = 0; rr < 4; rr++) pk[rr] = (bf16)(acc[mi][nt][rr] + bvv);
          *(bf16x4*)&myep[lm * 40 + mi * 16 + quad * 4] = pk;
        }
        int dl = lane >> 2, toff = (lane & 3) * 8;
        bf16x8 v = *(const bf16x8*)&myep[dl * 40 + toff];
        *(bf16x8*)(VTo + bhoff + (size_t)(nt * 16 + dl) * T_SEQ + t0w + toff) = v;
      }
    } else {
      // Q or K -> [bh][t][d]: 2 chunks of [16 t][64 d], stride 72
      bf16* dst = (mat == 0) ? Qo : Ko;
      const float* bias = (mat == 0) ? bq : bk;
#pragma unroll
      for (int c = 0; c < 2; c++) {
#pragma unroll
        for (int nt = 0; nt < 4; nt++) {
          int d = nt * 16 + lm;
          float bval = bias[nloc + d];
#pragma unroll
          for (int rr = 0; rr < 4; rr++) {
            float v = acc[c][nt][rr] + bval;
            if (mat == 1) v += pe_val(t0w + c * 16 + quad * 4 + rr, d);
            else          v *= 0.125f;   // fold 1/sqrt(dk) into Q
            myep[(quad * 4 + rr) * 72 + d] = (bf16)v;
          }
        }
#pragma unroll
        for (int rd = 0; rd < 2; rd++) {
          int row = rd * 8 + (lane >> 3);
          bf16x8 v = *(const bf16x8*)&myep[row * 72 + (lane & 7) * 8];
          *(bf16x8*)(dst + bhoff + (size_t)(t0w + c * 16 + row) * D_K + (lane & 7) * 8) = v;
        }
      }
    }
  }
}

// ---------------------------------------------------------------------------
// Output projection v4 — weights-resident LDS GEMM. out f32 = ctx@wo^T + bo.
// Grid (64, 8) = 512 blocks = exactly 2/CU. Block: 128m x 64n, 1 m-iter.
// LDS = 64KB W only (f32 stores are naturally full-line, no ep needed).
// ---------------------------------------------------------------------------
__global__ __launch_bounds__(256, 2) void gemm_out(const bf16* __restrict__ A,
                                                   const bf16* __restrict__ W,
                                                   const float* __restrict__ bias,
                                                   float* __restrict__ out) {
  __shared__ bf16 sW[32768];
  int tid = threadIdx.x;
  int w = tid >> 6, lane = tid & 63;
  int lm = lane & 15, quad = lane >> 4;
  int n0 = blockIdx.y * 64;

  {
    int row = tid >> 2;
    int cc  = (tid & 3) * 16;
#pragma unroll
    for (int kc = 0; kc < 8; kc++) {
      const bf16* src = W + (size_t)(n0 + row) * D_MODEL + kc * 64 + cc;
      bf16x8 w0 = *(const bf16x8*)src;
      bf16x8 w1 = *(const bf16x8*)(src + 8);
      *(bf16x8*)&sW[kc * 4096 + SWZ(row, cc)]     = w0;
      *(bf16x8*)&sW[kc * 4096 + SWZ(row, cc + 8)] = w1;
    }
  }
  __syncthreads();

  int mbase = blockIdx.x * 128 + w * 32;
  const bf16* ap = A + (size_t)(mbase + lm) * D_MODEL + quad * 8;

  bf16x8 af[2][16];
#pragma unroll
  for (int mi = 0; mi < 2; mi++)
#pragma unroll
    for (int ks = 0; ks < 16; ks++)
      af[mi][ks] = *(const bf16x8*)(ap + mi * 16 * D_MODEL + ks * 32);

  floatx4 acc[2][4];
#pragma unroll
  for (int mi = 0; mi < 2; mi++)
#pragma unroll
    for (int nt = 0; nt < 4; nt++) acc[mi][nt] = floatx4{0.f, 0.f, 0.f, 0.f};

#pragma unroll
  for (int ks = 0; ks < 16; ks++) {
#pragma unroll
    for (int nt = 0; nt < 4; nt++) {
      bf16x8 bfr = *(const bf16x8*)
          &sW[(ks >> 1) * 4096 + SWZ(nt * 16 + lm, (ks & 1) * 32 + quad * 8)];
      acc[0][nt] = __builtin_amdgcn_mfma_f32_16x16x32_bf16(af[0][ks], bfr, acc[0][nt], 0, 0, 0);
      acc[1][nt] = __builtin_amdgcn_mfma_f32_16x16x32_bf16(af[1][ks], bfr, acc[1][nt], 0, 0, 0);
    }
  }

#pragma unroll
  for (int nt = 0; nt < 4; nt++) {
    int n = n0 + nt * 16 + lm;
    float bval = bias[n];
#pragma unroll
    for (int mi = 0; mi < 2; mi++)
#pragma unroll
      for (int rr = 0; rr < 4; rr++) {
        int m = mbase + mi * 16 + quad * 4 + rr;
        out[(size_t)m * D_MODEL + n] = acc[mi][nt][rr] + bval;
      }
  }
}

// ---------------------------------------------------------------------------
// MFMA flash attention v3 (unchanged — validated).
// ---------------------------------------------------------------------------
__global__ __launch_bounds__(256) void flash_mfma(const bf16* __restrict__ Q,
                                                  const bf16* __restrict__ K,
                                                  const bf16* __restrict__ VT,
                                                  bf16* __restrict__ ctx) {
  __shared__ bf16 sK[64 * 64];          // [key][d]   8 KB, swizzled
  __shared__ bf16 sVT[64 * 64];         // [d][key]   8 KB, swizzled
  __shared__ bf16 sP[4][32 * 64];       // per-wave [q][key] 16 KB, swizzled

  int tid  = threadIdx.x;
  int wave = tid >> 6, lane = tid & 63;
  int lm = lane & 15, quad = lane >> 4;
  int bh = blockIdx.y;
  int q0 = blockIdx.x * 128 + wave * 32;

  const bf16* Qb  = Q  + (size_t)bh * T_SEQ * D_K;
  const bf16* Kb  = K  + (size_t)bh * T_SEQ * D_K;
  const bf16* VTb = VT + (size_t)bh * T_SEQ * D_K;  // [d][t]

  bf16x8 qf[2][2];
#pragma unroll
  for (int qt = 0; qt < 2; qt++)
#pragma unroll
    for (int kb = 0; kb < 2; kb++)
      qf[qt][kb] = *(const bf16x8*)(Qb + (size_t)(q0 + qt * 16 + lm) * D_K + kb * 32 + quad * 8);

  floatx4 o[2][4];
#pragma unroll
  for (int qt = 0; qt < 2; qt++)
#pragma unroll
    for (int nt = 0; nt < 4; nt++) o[qt][nt] = floatx4{0.f, 0.f, 0.f, 0.f};
  float l_i[2] = {0.f, 0.f};

  int srow = wave * 16 + (lane >> 2);
  int scol = (lane & 3) * 16;
  const bf16* kp0 = Kb  + (size_t)srow * D_K + scol;
  const bf16* vp0 = VTb + (size_t)srow * T_SEQ + scol;

  bf16x8 rk0 = *(const bf16x8*)(kp0);
  bf16x8 rk1 = *(const bf16x8*)(kp0 + 8);
  bf16x8 rv0 = *(const bf16x8*)(vp0);
  bf16x8 rv1 = *(const bf16x8*)(vp0 + 8);

  for (int kt = 0; kt < T_SEQ / 64; kt++) {
    __syncthreads();
    *(bf16x8*)&sK[SWZ(srow, scol)]      = rk0;
    *(bf16x8*)&sK[SWZ(srow, scol + 8)]  = rk1;
    *(bf16x8*)&sVT[SWZ(srow, scol)]     = rv0;
    *(bf16x8*)&sVT[SWZ(srow, scol + 8)] = rv1;
    if (kt + 1 < T_SEQ / 64) {
      const bf16* kp = kp0 + (size_t)(kt + 1) * 64 * D_K;
      const bf16* vp = vp0 + (size_t)(kt + 1) * 64;
      rk0 = *(const bf16x8*)(kp);
      rk1 = *(const bf16x8*)(kp + 8);
      rv0 = *(const bf16x8*)(vp);
      rv1 = *(const bf16x8*)(vp + 8);
    }
    __syncthreads();

    floatx4 s[2][4];
#pragma unroll
    for (int qt = 0; qt < 2; qt++)
#pragma unroll
      for (int nt = 0; nt < 4; nt++) s[qt][nt] = floatx4{0.f, 0.f, 0.f, 0.f};
#pragma unroll
    for (int kb = 0; kb < 2; kb++) {
#pragma unroll
      for (int nt = 0; nt < 4; nt++) {
        bf16x8 kf = *(const bf16x8*)&sK[SWZ(nt * 16 + lm, kb * 32 + quad * 8)];
        s[0][nt] = __builtin_amdgcn_mfma_f32_16x16x32_bf16(kf, qf[0][kb], s[0][nt], 0, 0, 0);
        s[1][nt] = __builtin_amdgcn_mfma_f32_16x16x32_bf16(kf, qf[1][kb], s[1][nt], 0, 0, 0);
      }
    }

#pragma unroll
    for (int qt = 0; qt < 2; qt++) {
      float ls = 0.f;
      bf16x4 pk[4];
#pragma unroll
      for (int nt = 0; nt < 4; nt++) {
#pragma unroll
        for (int rr = 0; rr < 4; rr++) {
          float p = __expf(s[qt][nt][rr] - 8.0f);
          ls += p;
          pk[nt][rr] = (bf16)p;
        }
      }
#pragma unroll
      for (int nt = 0; nt < 4; nt++)
        *(bf16x4*)&sP[wave][SWZ(qt * 16 + lm, nt * 16 + quad * 4)] = pk[nt];
      ls += __shfl_xor(ls, 16, 64);
      ls += __shfl_xor(ls, 32, 64);
      l_i[qt] += ls;
    }

#pragma unroll
    for (int kb = 0; kb < 2; kb++) {
      bf16x8 pf0 = *(const bf16x8*)&sP[wave][SWZ(lm, kb * 32 + quad * 8)];
      bf16x8 pf1 = *(const bf16x8*)&sP[wave][SWZ(16 + lm, kb * 32 + quad * 8)];
#pragma unroll
      for (int nt = 0; nt < 4; nt++) {
        bf16x8 vt = *(const bf16x8*)&sVT[SWZ(nt * 16 + lm, kb * 32 + quad * 8)];
        o[0][nt] = __builtin_amdgcn_mfma_f32_16x16x32_bf16(pf0, vt, o[0][nt], 0, 0, 0);
        o[1][nt] = __builtin_amdgcn_mfma_f32_16x16x32_bf16(pf1, vt, o[1][nt], 0, 0, 0);
      }
    }
  }

  int b_ = bh >> 3, h = bh & 7;
#pragma unroll
  for (int qt = 0; qt < 2; qt++) {
#pragma unroll
    for (int rr = 0; rr < 4; rr++) {
      int qq = quad * 4 + rr;
      float linv = 1.f / __shfl(l_i[qt], qq, 64);
      int t = q0 + qt * 16 + qq;
      bf16* op = ctx + ((size_t)(b_ * T_SEQ + t)) * D_MODEL + h * D_K;
#pragma unroll
      for (int nt = 0; nt < 4; nt++)
        op[nt * 16 + lm] = (bf16)(o[qt][nt][rr] * linv);
    }
  }
}

// ---------------------------------------------------------------------------
extern "C" void kernel_launch(void* const* d_in, const int* in_sizes, int n_in,
                              void* d_out, int out_size, void* d_ws, size_t ws_size,
                              hipStream_t stream) {
  const float* x    = (const float*)d_in[0];
  const float* ln_g = (const float*)d_in[1];
  const float* ln_b = (const float*)d_in[2];
  const float* wq   = (const float*)d_in[3];
  const float* bq   = (const float*)d_in[4];
  const float* wk   = (const float*)d_in[5];
  const float* bk   = (const float*)d_in[6];
  const float* wv   = (const float*)d_in[7];
  const float* bv   = (const float*)d_in[8];
  const float* wo   = (const float*)d_in[9];
  const float* bo   = (const float*)d_in[10];
  float* out = (float*)d_out;

  char* ws = (char*)d_ws;
  const size_t MB8 = (size_t)M_ROWS * D_MODEL * sizeof(bf16);  // 8 MB
  bf16* normed = (bf16*)(ws);                    // dead after gemm_qkv
  bf16* Qb     = (bf16*)(ws + MB8);
  bf16* Kb     = (bf16*)(ws + 2 * MB8);
  bf16* VTb    = (bf16*)(ws + 3 * MB8);          // V^T: [bh][d][t]
  bf16* w4     = (bf16*)(ws + 4 * MB8);          // 2 MB: wq|wk|wv|wo bf16
  bf16* ctx    = normed;                         // alias; ws total 34 MB

  prep<<<M_ROWS + 1024, 256, 0, stream>>>(x, ln_g, ln_b, normed,
                                          wq, wk, wv, wo, w4);
  gemm_qkv<<<dim3(32, 24), 256, 0, stream>>>(
      normed, w4, bq, bk, bv, Qb, Kb, VTb);
  flash_mfma<<<dim3(T_SEQ / 128, B_SZ * N_HEADS), 256, 0, stream>>>(Qb, Kb, VTb, ctx);
  gemm_out<<<dim3(64, 8), 256, 0, stream>>>(
      ctx, w4 + 3 * (size_t)D_MODEL * D_MODEL, bo, out);
}